// Round 1
// baseline (205.826 us; speedup 1.0000x reference)
//
#include <hip/hip_runtime.h>

// Problem constants
constexpr int NB  = 1024;
constexpr int NIN = 512;
constexpr int NJ  = 64;
constexpr int NK  = 8;
constexpr int NC  = NJ * NK;          // 512
constexpr int OUTC = NIN + NJ;        // 576
constexpr float EXPN10 = 4.5399929762484854e-05f;
constexpr float FEAT_BASE = 1024.0f * EXPN10;

constexpr unsigned GRID2 = 1024;      // fused kernel grid (must all be co-resident)

typedef __bf16 bf16x8 __attribute__((ext_vector_type(8)));
typedef float floatx16 __attribute__((ext_vector_type(16)));

__device__ __forceinline__ unsigned f2bf(float f) {  // RNE fp32->bf16
  unsigned u = __float_as_uint(f);
  u += 0x7FFFu + ((u >> 16) & 1u);
  return u >> 16;
}

// ---------------------------------------------------------------------------
// Kernel 1: conversions only (out-init moved into fused kernel phase 1).
//   [0,256)   : x fp32 -> xb bf16
//   [256,320) : T fp32 [i][c] -> Tt bf16 [c][i] (64x64 LDS transpose tiles)
// Also zeroes the grid-barrier counter for kernel 2 (stream order publishes it).
// ---------------------------------------------------------------------------
__global__ __launch_bounds__(256) void conv_kernel(const float* __restrict__ x,
                                                   const float* __restrict__ T,
                                                   uint4* __restrict__ xb,
                                                   ushort* __restrict__ Tt,
                                                   unsigned* __restrict__ cnt) {
  __shared__ float Ts[64][65];
  const int bid = blockIdx.x;
  const int tid = threadIdx.x;

  if (bid == 0 && tid == 0) *cnt = 0u;   // barrier counter init for kernel 2

  if (bid < 256) {              // ---- conv_x ----
    const int idx = bid * 256 + tid;            // 0..65535
    const float4 v0 = ((const float4*)x)[idx * 2];
    const float4 v1 = ((const float4*)x)[idx * 2 + 1];
    uint4 p;
    p.x = f2bf(v0.x) | (f2bf(v0.y) << 16);
    p.y = f2bf(v0.z) | (f2bf(v0.w) << 16);
    p.z = f2bf(v1.x) | (f2bf(v1.y) << 16);
    p.w = f2bf(v1.z) | (f2bf(v1.w) << 16);
    xb[idx] = p;
  } else {                      // ---- conv_T (transpose + bf16) ----
    const int t = bid - 256;
    const int i0 = (t & 7) * 64;
    const int c0 = (t >> 3) * 64;

    const int ti4 = (tid >> 4) * 4;
    const int tc  = (tid & 15) * 4;
#pragma unroll
    for (int r = 0; r < 4; ++r) {
      const float4 v = *(const float4*)&T[(i0 + ti4 + r) * NC + c0 + tc];
      Ts[tc + 0][ti4 + r] = v.x;
      Ts[tc + 1][ti4 + r] = v.y;
      Ts[tc + 2][ti4 + r] = v.z;
      Ts[tc + 3][ti4 + r] = v.w;
    }
    __syncthreads();

    const int co = tid >> 2;
    const int io = (tid & 3) * 16;
    unsigned w[8];
#pragma unroll
    for (int q = 0; q < 8; ++q)
      w[q] = f2bf(Ts[co][io + 2 * q]) | (f2bf(Ts[co][io + 2 * q + 1]) << 16);
    uint4* dst = (uint4*)&Tt[(size_t)(c0 + co) * NIN + i0 + io];
    dst[0] = uint4{w[0], w[1], w[2], w[3]};
    dst[1] = uint4{w[4], w[5], w[6], w[7]};
  }
}

// ---------------------------------------------------------------------------
// Kernel 2 (fused): grid 1024 x 256, __launch_bounds__(256,4) + 34816 B LDS
// guarantee 4 blocks/CU -> all 1024 blocks co-resident -> soft grid barrier
// is deadlock-free.
//   Phase 1: blocks [0,128): gemm 64x64 tile (identical to proven R8 body,
//            epilogue emits Mp/Mb/na). Blocks [128,1024): out init
//            (out[b][0:512]=x[b], out[b][512:576]=FEAT_BASE).
//   Barrier: device-scope release/acquire (threadfence + agent atomics).
//   Phase 2: all blocks: pairwise (identical to proven R5/R8 body), LDS
//            overlaid on the gemm arena.
// ---------------------------------------------------------------------------
__global__ __launch_bounds__(256, 4) void fused_kernel(const uint4* __restrict__ xb,
                                                       const uint4* __restrict__ ttb,
                                                       const float* __restrict__ x,
                                                       float* __restrict__ Mp,
                                                       uint4* __restrict__ Mb,
                                                       float* __restrict__ na,
                                                       float* __restrict__ out,
                                                       unsigned* __restrict__ cnt) {
  __shared__ __align__(16) unsigned char smem[2 * 64 * 136 * 2];   // 34816 B
  const int tid = threadIdx.x;
  const int bid = blockIdx.x;

  // ======================= Phase 1 =======================
  if (bid < 128) {
    // ---- gemm ----
    ushort* Xs = (ushort*)smem;               // [64][136] bf16
    ushort* Ts = (ushort*)smem + 64 * 136;    // [64][136] bf16
    float*  Cs = (float*)smem;                // [64][68] fp32 epilogue tile

    const int b0 = (bid & 15) * 64;
    const int c0 = (bid >> 4) * 64;

    const int lane = tid & 63;
    const int w    = tid >> 6;
    const int l31  = lane & 31;
    const int half = lane >> 5;
    const int arow = (w & 1) * 32 + l31;
    const int bcol = (w >> 1) * 32 + l31;

    floatx16 acc = {};

    for (int z = 0; z < 4; ++z) {
#pragma unroll
      for (int t = 0; t < 4; ++t) {
        const int u = t * 256 + tid;
        const int row = u >> 4, seg = u & 15;
        *(uint4*)&Xs[row * 136 + seg * 8] = xb[(b0 + row) * 64 + z * 16 + seg];
        *(uint4*)&Ts[row * 136 + seg * 8] = ttb[(c0 + row) * 64 + z * 16 + seg];
      }
      __syncthreads();

#pragma unroll
      for (int s = 0; s < 8; ++s) {
        const bf16x8 af = *(const bf16x8*)&Xs[arow * 136 + s * 16 + half * 8];
        const bf16x8 bf = *(const bf16x8*)&Ts[bcol * 136 + s * 16 + half * 8];
        acc = __builtin_amdgcn_mfma_f32_32x32x16_bf16(af, bf, acc, 0, 0, 0);
      }
      __syncthreads();
    }

    // ---- epilogue: acc -> Cs (stride 68), then prep rows ----
#pragma unroll
    for (int reg = 0; reg < 16; ++reg) {
      const int row = (reg & 3) + 8 * (reg >> 2) + 4 * half;
      Cs[((w & 1) * 32 + row) * 68 + (w >> 1) * 32 + l31] = acc[reg];
    }
    __syncthreads();

#pragma unroll
    for (int pass = 0; pass < 2; ++pass) {
      const int jl = (tid >> 6) + pass * 4;   // local j 0..7
      const int b  = tid & 63;                // local b
      const float4 m0 = *(const float4*)&Cs[b * 68 + jl * 8];
      const float4 m1 = *(const float4*)&Cs[b * 68 + jl * 8 + 4];
      const int j_g = (bid >> 4) * 8 + jl;
      const int idx = j_g * NB + b0 + b;
      ((float4*)Mp)[idx * 2]     = m0;
      ((float4*)Mp)[idx * 2 + 1] = m1;
      float s = m0.x * m0.x;
      s = fmaf(m0.y, m0.y, s); s = fmaf(m0.z, m0.z, s); s = fmaf(m0.w, m0.w, s);
      s = fmaf(m1.x, m1.x, s); s = fmaf(m1.y, m1.y, s); s = fmaf(m1.z, m1.z, s);
      s = fmaf(m1.w, m1.w, s);
      na[idx] = s;
      uint4 pk;
      pk.x = f2bf(m0.x) | (f2bf(m0.y) << 16);
      pk.y = f2bf(m0.z) | (f2bf(m0.w) << 16);
      pk.z = f2bf(m1.x) | (f2bf(m1.y) << 16);
      pk.w = f2bf(m1.z) | (f2bf(m1.w) << 16);
      Mb[idx] = pk;
    }
  } else {
    // ---- out init (147456 float4 total over blocks 128..703) ----
    const int gi = (bid - 128) * 256 + tid;
    if (gi < (NB * OUTC) / 4) {
      const int b = gi / (OUTC / 4);          // /144 -> magic mul
      const int r = gi - b * (OUTC / 4);
      float4 v;
      if (r < NIN / 4) v = ((const float4*)x)[b * (NIN / 4) + r];
      else v = float4{FEAT_BASE, FEAT_BASE, FEAT_BASE, FEAT_BASE};
      ((float4*)out)[gi] = v;
    }
  }

  // ======================= grid barrier =======================
  __syncthreads();
  if (tid == 0) {
    __threadfence();   // release: publish Mp/Mb/na/out device-wide
    __hip_atomic_fetch_add(cnt, 1u, __ATOMIC_ACQ_REL, __HIP_MEMORY_SCOPE_AGENT);
    while (__hip_atomic_load(cnt, __ATOMIC_ACQUIRE, __HIP_MEMORY_SCOPE_AGENT) < GRID2)
      __builtin_amdgcn_s_sleep(2);
    __threadfence();   // acquire: invalidate caches before phase-2 reads
  }
  __syncthreads();

  // ======================= Phase 2: pairwise =======================
  const int j    = bid & 63;
  const int ag   = (bid >> 6) & 7;
  const int bh   = bid >> 9;
  const int lane = tid & 63;
  const int w    = tid >> 6;
  const int col  = lane & 31;
  const int h    = lane >> 5;
  const int jb   = j * NB;

  uint4* Mb_s = (uint4*)smem;                       // [513] (8208 B)
  float* nb_s = (float*)(smem + 8208);              // [512] (2048 B)
  float* na_s = (float*)(smem + 10256);             // [128] (512 B)

  const int bbeg = bh * 512;
  Mb_s[tid]       = Mb[jb + bbeg + tid];
  Mb_s[tid + 256] = Mb[jb + bbeg + tid + 256];
  nb_s[tid]       = na[jb + bbeg + tid];
  nb_s[tid + 256] = na[jb + bbeg + tid + 256];
  if (tid == 0) Mb_s[512] = uint4{0u, 0u, 0u, 0u};

  const int a0 = ag * 128 + w * 32;
  if (lane < 32) na_s[w * 32 + lane] = na[jb + a0 + lane];

  uint4 araw = uint4{0u, 0u, 0u, 0u};
  if (lane < 32) araw = Mb[jb + a0 + lane];
  const bf16x8 af = __builtin_bit_cast(bf16x8, araw);

  __syncthreads();

  float c995[16];
#pragma unroll
  for (int reg = 0; reg < 16; ++reg) {
    const int row = (reg & 3) + 8 * (reg >> 2) + 4 * h;
    c995[reg] = 0.995f * na_s[w * 32 + row];
  }

  const floatx16 zero = {};

#pragma unroll 2
  for (int bt = 0; bt < 16; ++bt) {
    const int bidx = bt * 32 + col;
    const uint4 braw = Mb_s[lane < 32 ? bidx : 512];
    const bf16x8 bf = __builtin_bit_cast(bf16x8, braw);
    const floatx16 P = __builtin_amdgcn_mfma_f32_32x32x16_bf16(af, bf, zero, 0, 0, 0);
    const float nb_l = nb_s[bidx];
    const float rhs = 100.0f - 0.995f * nb_l;

    float t = fmaf(-2.0f, P[0], c995[0]);
#pragma unroll
    for (int reg = 1; reg < 16; ++reg)
      t = fminf(t, fmaf(-2.0f, P[reg], c995[reg]));

    if (__any(t < rhs)) {   // rare: ~diagonal tiles only
#pragma unroll
      for (int reg = 0; reg < 16; ++reg) {
        if (fmaf(-2.0f, P[reg], c995[reg]) < rhs) {
          const int row = (reg & 3) + 8 * (reg >> 2) + 4 * h;
          const int a = a0 + row;
          const int b = bbeg + bt * 32 + col;
          float corr;
          if (a == b) {
            corr = 1.0f - EXPN10;
          } else {
            const float4 av0 = ((const float4*)Mp)[(jb + a) * 2];
            const float4 av1 = ((const float4*)Mp)[(jb + a) * 2 + 1];
            const float4 bv0 = ((const float4*)Mp)[(jb + b) * 2];
            const float4 bv1 = ((const float4*)Mp)[(jb + b) * 2 + 1];
            float d = av0.x - bv0.x; float sq = d * d;
            d = av0.y - bv0.y; sq = fmaf(d, d, sq);
            d = av0.z - bv0.z; sq = fmaf(d, d, sq);
            d = av0.w - bv0.w; sq = fmaf(d, d, sq);
            d = av1.x - bv1.x; sq = fmaf(d, d, sq);
            d = av1.y - bv1.y; sq = fmaf(d, d, sq);
            d = av1.z - bv1.z; sq = fmaf(d, d, sq);
            d = av1.w - bv1.w; sq = fmaf(d, d, sq);
            const float nrm = sqrtf(sq);
            corr = (nrm < 10.0f) ? (__expf(-nrm) - EXPN10) : 0.0f;
          }
          if (corr != 0.0f) atomicAdd(&out[a * OUTC + NIN + j], corr);
        }
      }
    }
  }
}

// ---------------------------------------------------------------------------
extern "C" void kernel_launch(void* const* d_in, const int* in_sizes, int n_in,
                              void* d_out, int out_size, void* d_ws, size_t ws_size,
                              hipStream_t stream) {
  const float* x = (const float*)d_in[0];
  const float* T = (const float*)d_in[1];
  float* out = (float*)d_out;

  // workspace layout (4.75 MB used + barrier counter at 8 MB)
  float* Mp  = (float*)d_ws;                         // [64][1024][8] fp32   2 MB
  float* na  = Mp + (size_t)NJ * NB * NK;            // [64][1024]         256 KB
  uint4* Mb  = (uint4*)(na + (size_t)NJ * NB);       // [64][1024] bf16x8    1 MB
  uint4* xb  = Mb + (size_t)NJ * NB;                 // [1024][512] bf16     1 MB
  ushort* Tt = (ushort*)(xb + (size_t)NB * NIN / 8); // [512][512] bf16    0.5 MB
  unsigned* cnt = (unsigned*)((char*)d_ws + (8u << 20));

  conv_kernel<<<dim3(320), 256, 0, stream>>>(x, T, xb, Tt, cnt);
  fused_kernel<<<dim3(GRID2), 256, 0, stream>>>(xb, (const uint4*)Tt, x, Mp, Mb, na, out, cnt);
}

// Round 3
// 106.278 us; speedup vs baseline: 1.9367x; 1.9367x over previous
//
#include <hip/hip_runtime.h>

// Problem constants
constexpr int NB  = 1024;
constexpr int NIN = 512;
constexpr int NJ  = 64;
constexpr int NK  = 8;
constexpr int NC  = NJ * NK;          // 512
constexpr int OUTC = NIN + NJ;        // 576
constexpr float EXPN10 = 4.5399929762484854e-05f;
constexpr float FEAT_BASE = 1024.0f * EXPN10;

typedef __bf16 bf16x8 __attribute__((ext_vector_type(8)));
typedef float floatx16 __attribute__((ext_vector_type(16)));

__device__ __forceinline__ unsigned f2bf(float f) {  // RNE fp32->bf16
  unsigned u = __float_as_uint(f);
  u += 0x7FFFu + ((u >> 16) & 1u);
  return u >> 16;
}

// ---------------------------------------------------------------------------
// Kernel 1 (gemm_fused): grid 16x8 = 128 blocks, 4 waves, 34816 B LDS
// (same footprint as the PROVEN 73.7us gemm — no 130KB experiment).
// Differences vs proven R0 gemm:
//   - inputs are raw fp32 x / T: conversion to bf16 happens inline during
//     LDS staging (A: coalesced float4x2 -> pack; B: coalesced row read ->
//     scalar ds_write_b16 transposed column, 8-way bank conflict ~2.9x on
//     32 writes/thread/z — ~0.15us, accepted).
//   - out-init folded in as independent prologue work.
// This removes the conv dispatch entirely. No grid barrier (R1 lesson:
// acquire-spin = device-wide cache invalidate storm, 155us).
// ---------------------------------------------------------------------------
__global__ __launch_bounds__(256) void gemm_fused(const float* __restrict__ x,
                                                  const float* __restrict__ T,
                                                  float* __restrict__ Mp,
                                                  uint4* __restrict__ Mb,
                                                  float* __restrict__ na,
                                                  float* __restrict__ out) {
  __shared__ __align__(16) ushort smem_u[2 * 64 * 136];   // 34816 B
  ushort* Xs = smem_u;              // [64][136] bf16 : A tile (b rows, 128 k)
  ushort* Ts = smem_u + 64 * 136;   // [64][136] bf16 : B tile (c rows, 128 k)
  float*  Cs = (float*)smem_u;      // [64][68] fp32 epilogue tile (overlay)

  const int tid = threadIdx.x;
  const int b0 = blockIdx.x * 64;
  const int c0 = blockIdx.y * 64;

  const int lane = tid & 63;
  const int w    = tid >> 6;
  const int l31  = lane & 31;
  const int half = lane >> 5;
  const int arow = (w & 1) * 32 + l31;
  const int bcol = (w >> 1) * 32 + l31;

  // ---- out init (independent work; out consumed only by pairwise dispatch)
  const int bidf = blockIdx.y * 16 + blockIdx.x;   // 0..127
#pragma unroll
  for (int it = 0; it < 5; ++it) {
    const int li = it * 256 + tid;
    if (li < 1152) {                                 // 147456/128 float4 per block
      const int gi = bidf * 1152 + li;
      const int b = gi / (OUTC / 4);                 // /144 -> magic mul
      const int r = gi - b * (OUTC / 4);
      float4 v;
      if (r < NIN / 4) v = ((const float4*)x)[b * (NIN / 4) + r];
      else v = float4{FEAT_BASE, FEAT_BASE, FEAT_BASE, FEAT_BASE};
      ((float4*)out)[gi] = v;
    }
  }

  floatx16 acc = {};

  for (int z = 0; z < 4; ++z) {
    // ---- stage A: x fp32 -> Xs bf16 (coalesced float4x2 + pack) ----
#pragma unroll
    for (int t = 0; t < 4; ++t) {
      const int u = t * 256 + tid;          // 0..1023 uint4-slots
      const int row = u >> 4;               // 0..63
      const int seg = u & 15;               // 0..15 (8 bf16 each)
      const float4 v0 = *(const float4*)&x[(size_t)(b0 + row) * NIN + z * 128 + seg * 8];
      const float4 v1 = *(const float4*)&x[(size_t)(b0 + row) * NIN + z * 128 + seg * 8 + 4];
      uint4 p;
      p.x = f2bf(v0.x) | (f2bf(v0.y) << 16);
      p.y = f2bf(v0.z) | (f2bf(v0.w) << 16);
      p.z = f2bf(v1.x) | (f2bf(v1.y) << 16);
      p.w = f2bf(v1.z) | (f2bf(v1.w) << 16);
      *(uint4*)&Xs[row * 136 + seg * 8] = p;
    }

    // ---- stage B: T fp32 [k][c] -> Ts bf16 [c][k] (in-block transpose) ----
    // per iter: wave reads 64 contiguous floats of one T row (256B coalesced),
    // writes one transposed LDS column (scalar b16).
#pragma unroll
    for (int i = 0; i < 32; ++i) {
      const int kk = i * 4 + w;             // 0..127 within z-slice
      const float v = T[(size_t)(z * 128 + kk) * NC + c0 + lane];
      Ts[lane * 136 + kk] = (ushort)f2bf(v);
    }

    __syncthreads();

    // ---- MFMA: 8 steps of K=16 ----
#pragma unroll
    for (int s = 0; s < 8; ++s) {
      const bf16x8 af = *(const bf16x8*)&Xs[arow * 136 + s * 16 + half * 8];
      const bf16x8 bf = *(const bf16x8*)&Ts[bcol * 136 + s * 16 + half * 8];
      acc = __builtin_amdgcn_mfma_f32_32x32x16_bf16(af, bf, acc, 0, 0, 0);
    }
    __syncthreads();
  }

  // ---- epilogue: acc -> Cs (stride 68, conflict-free), then prep rows ----
#pragma unroll
  for (int reg = 0; reg < 16; ++reg) {
    const int row = (reg & 3) + 8 * (reg >> 2) + 4 * half;
    Cs[((w & 1) * 32 + row) * 68 + (w >> 1) * 32 + l31] = acc[reg];
  }
  __syncthreads();

#pragma unroll
  for (int pass = 0; pass < 2; ++pass) {
    const int jl = (tid >> 6) + pass * 4;   // local j 0..7
    const int b  = tid & 63;                // local b
    const float4 m0 = *(const float4*)&Cs[b * 68 + jl * 8];
    const float4 m1 = *(const float4*)&Cs[b * 68 + jl * 8 + 4];
    const int j_g = blockIdx.y * 8 + jl;
    const int idx = j_g * NB + b0 + b;
    ((float4*)Mp)[idx * 2]     = m0;
    ((float4*)Mp)[idx * 2 + 1] = m1;
    float s = m0.x * m0.x;
    s = fmaf(m0.y, m0.y, s); s = fmaf(m0.z, m0.z, s); s = fmaf(m0.w, m0.w, s);
    s = fmaf(m1.x, m1.x, s); s = fmaf(m1.y, m1.y, s); s = fmaf(m1.z, m1.z, s);
    s = fmaf(m1.w, m1.w, s);
    na[idx] = s;
    uint4 pk;
    pk.x = f2bf(m0.x) | (f2bf(m0.y) << 16);
    pk.y = f2bf(m0.z) | (f2bf(m0.w) << 16);
    pk.z = f2bf(m1.x) | (f2bf(m1.y) << 16);
    pk.w = f2bf(m1.z) | (f2bf(m1.w) << 16);
    Mb[idx] = pk;
  }
}

// ---------------------------------------------------------------------------
// Kernel 2: pairwise via MFMA + exact per-pair prefilter; corrections go
// straight into out[b][512+j] (out pre-initialized with FEAT_BASE).
// flag iff 0.995*(na+nb) - 2P < 100 (no false negatives; FP rate ~1e-5).
// (byte-identical to the proven 73.7us version)
// ---------------------------------------------------------------------------
__global__ __launch_bounds__(256) void pairwise_kernel(const uint4* __restrict__ Mb,
                                                       const float* __restrict__ na,
                                                       const float* __restrict__ Mp,
                                                       float* __restrict__ out) {
  const int j    = blockIdx.x;
  const int ag   = blockIdx.y;
  const int bh   = blockIdx.z;
  const int tid  = threadIdx.x;
  const int lane = tid & 63;
  const int w    = tid >> 6;
  const int col  = lane & 31;
  const int h    = lane >> 5;
  const int jb   = j * NB;

  __shared__ uint4 Mb_s[513];    // [512] = zeros for K-pad lanes
  __shared__ float nb_s[512];
  __shared__ float na_s[128];

  const int bbeg = bh * 512;
  Mb_s[tid]       = Mb[jb + bbeg + tid];
  Mb_s[tid + 256] = Mb[jb + bbeg + tid + 256];
  nb_s[tid]       = na[jb + bbeg + tid];
  nb_s[tid + 256] = na[jb + bbeg + tid + 256];
  if (tid == 0) Mb_s[512] = uint4{0u, 0u, 0u, 0u};

  const int a0 = ag * 128 + w * 32;
  if (lane < 32) na_s[w * 32 + lane] = na[jb + a0 + lane];

  uint4 araw = uint4{0u, 0u, 0u, 0u};
  if (lane < 32) araw = Mb[jb + a0 + lane];
  const bf16x8 af = __builtin_bit_cast(bf16x8, araw);

  __syncthreads();

  float c995[16];
#pragma unroll
  for (int reg = 0; reg < 16; ++reg) {
    const int row = (reg & 3) + 8 * (reg >> 2) + 4 * h;
    c995[reg] = 0.995f * na_s[w * 32 + row];
  }

  const floatx16 zero = {};

#pragma unroll 2
  for (int bt = 0; bt < 16; ++bt) {
    const int bidx = bt * 32 + col;
    const uint4 braw = Mb_s[lane < 32 ? bidx : 512];
    const bf16x8 bf = __builtin_bit_cast(bf16x8, braw);
    const floatx16 P = __builtin_amdgcn_mfma_f32_32x32x16_bf16(af, bf, zero, 0, 0, 0);
    const float nb_l = nb_s[bidx];
    const float rhs = 100.0f - 0.995f * nb_l;

    float t = fmaf(-2.0f, P[0], c995[0]);
#pragma unroll
    for (int reg = 1; reg < 16; ++reg)
      t = fminf(t, fmaf(-2.0f, P[reg], c995[reg]));

    if (__any(t < rhs)) {   // rare: ~diagonal tiles only
#pragma unroll
      for (int reg = 0; reg < 16; ++reg) {
        if (fmaf(-2.0f, P[reg], c995[reg]) < rhs) {
          const int row = (reg & 3) + 8 * (reg >> 2) + 4 * h;
          const int a = a0 + row;
          const int b = bbeg + bt * 32 + col;
          float corr;
          if (a == b) {
            corr = 1.0f - EXPN10;
          } else {
            const float4 av0 = ((const float4*)Mp)[(jb + a) * 2];
            const float4 av1 = ((const float4*)Mp)[(jb + a) * 2 + 1];
            const float4 bv0 = ((const float4*)Mp)[(jb + b) * 2];
            const float4 bv1 = ((const float4*)Mp)[(jb + b) * 2 + 1];
            float d = av0.x - bv0.x; float sq = d * d;
            d = av0.y - bv0.y; sq = fmaf(d, d, sq);
            d = av0.z - bv0.z; sq = fmaf(d, d, sq);
            d = av0.w - bv0.w; sq = fmaf(d, d, sq);
            d = av1.x - bv1.x; sq = fmaf(d, d, sq);
            d = av1.y - bv1.y; sq = fmaf(d, d, sq);
            d = av1.z - bv1.z; sq = fmaf(d, d, sq);
            d = av1.w - bv1.w; sq = fmaf(d, d, sq);
            const float nrm = sqrtf(sq);
            corr = (nrm < 10.0f) ? (__expf(-nrm) - EXPN10) : 0.0f;
          }
          if (corr != 0.0f) atomicAdd(&out[a * OUTC + NIN + j], corr);
        }
      }
    }
  }
}

// ---------------------------------------------------------------------------
extern "C" void kernel_launch(void* const* d_in, const int* in_sizes, int n_in,
                              void* d_out, int out_size, void* d_ws, size_t ws_size,
                              hipStream_t stream) {
  const float* x = (const float*)d_in[0];
  const float* T = (const float*)d_in[1];
  float* out = (float*)d_out;

  // workspace layout (3.25 MB)
  float* Mp  = (float*)d_ws;                         // [64][1024][8] fp32   2 MB
  float* na  = Mp + (size_t)NJ * NB * NK;            // [64][1024]         256 KB
  uint4* Mb  = (uint4*)(na + (size_t)NJ * NB);       // [64][1024] bf16x8    1 MB

  gemm_fused<<<dim3(16, 8), 256, 0, stream>>>(x, T, Mp, Mb, na, out);
  pairwise_kernel<<<dim3(NJ, 8, 2), 256, 0, stream>>>(Mb, na, Mp, out);
}

// Round 4
// 74.689 us; speedup vs baseline: 2.7558x; 1.4229x over previous
//
#include <hip/hip_runtime.h>

// Problem constants
constexpr int NB  = 1024;
constexpr int NIN = 512;
constexpr int NJ  = 64;
constexpr int NK  = 8;
constexpr int NC  = NJ * NK;          // 512
constexpr int OUTC = NIN + NJ;        // 576
constexpr float EXPN10 = 4.5399929762484854e-05f;
constexpr float FEAT_BASE = 1024.0f * EXPN10;

typedef __bf16 bf16x8 __attribute__((ext_vector_type(8)));
typedef float floatx16 __attribute__((ext_vector_type(16)));

__device__ __forceinline__ unsigned f2bf(float f) {  // RNE fp32->bf16
  unsigned u = __float_as_uint(f);
  u += 0x7FFFu + ((u >> 16) & 1u);
  return u >> 16;
}

// ---------------------------------------------------------------------------
// Kernel 1 (gemm_fused): grid 16x8 = 128 blocks, 4 waves, 34816 B LDS.
// R3 lesson: scalar per-element T loads got compiled to load->waitcnt(0)->
// write per iteration (VGPR=52) = 128 serialized HBM round-trips = ~47us.
// Fix: explicit two-phase staging — batch ALL global loads for a z-slice
// into register arrays (16 independent dwordx4 in flight), then convert +
// write LDS. B transpose now reads float4 pairs from consecutive T rows and
// writes packed {k,k+1} b32 words (dword-aligned, 8-way conflict on 16
// writes/thread/z — negligible).
// ---------------------------------------------------------------------------
__global__ __launch_bounds__(256) void gemm_fused(const float* __restrict__ x,
                                                  const float* __restrict__ T,
                                                  float* __restrict__ Mp,
                                                  uint4* __restrict__ Mb,
                                                  float* __restrict__ na,
                                                  float* __restrict__ out) {
  __shared__ __align__(16) ushort smem_u[2 * 64 * 136];   // 34816 B
  ushort* Xs = smem_u;              // [64][136] bf16 : A tile (b rows, 128 k)
  ushort* Ts = smem_u + 64 * 136;   // [64][136] bf16 : B tile (c rows, 128 k)
  float*  Cs = (float*)smem_u;      // [64][68] fp32 epilogue tile (overlay)

  const int tid = threadIdx.x;
  const int b0 = blockIdx.x * 64;
  const int c0 = blockIdx.y * 64;

  const int lane = tid & 63;
  const int w    = tid >> 6;
  const int l31  = lane & 31;
  const int half = lane >> 5;
  const int arow = (w & 1) * 32 + l31;
  const int bcol = (w >> 1) * 32 + l31;

  // B-transpose thread mapping (fixed across z)
  const int pr   = tid >> 4;        // 0..15 : k-pair index within 32-row group
  const int coff = (tid & 15) * 4;  // 0..60 : c-quad offset

  // ---- out init (independent work; out consumed only by pairwise dispatch)
  const int bidf = blockIdx.y * 16 + blockIdx.x;   // 0..127
#pragma unroll
  for (int it = 0; it < 5; ++it) {
    const int li = it * 256 + tid;
    if (li < 1152) {                                 // 147456/128 float4 per block
      const int gi = bidf * 1152 + li;
      const int b = gi / (OUTC / 4);                 // /144 -> magic mul
      const int r = gi - b * (OUTC / 4);
      float4 v;
      if (r < NIN / 4) v = ((const float4*)x)[b * (NIN / 4) + r];
      else v = float4{FEAT_BASE, FEAT_BASE, FEAT_BASE, FEAT_BASE};
      ((float4*)out)[gi] = v;
    }
  }

  floatx16 acc = {};

  for (int z = 0; z < 4; ++z) {
    // ================= load phase: ALL global loads batched =================
    float4 av[8];
#pragma unroll
    for (int t = 0; t < 4; ++t) {
      const int u = t * 256 + tid;
      const int row = u >> 4, seg = u & 15;
      const size_t base = (size_t)(b0 + row) * NIN + z * 128 + seg * 8;
      av[2 * t]     = *(const float4*)&x[base];
      av[2 * t + 1] = *(const float4*)&x[base + 4];
    }
    float4 bv[8];
#pragma unroll
    for (int it = 0; it < 4; ++it) {
      const int k0 = it * 32 + pr * 2;               // local k (even), 0..126
      const size_t base = (size_t)(z * 128 + k0) * NC + c0 + coff;
      bv[2 * it]     = *(const float4*)&T[base];      // row k0
      bv[2 * it + 1] = *(const float4*)&T[base + NC]; // row k0+1
    }

    // ================= write phase: convert + LDS =================
#pragma unroll
    for (int t = 0; t < 4; ++t) {
      const int u = t * 256 + tid;
      const int row = u >> 4, seg = u & 15;
      uint4 p;
      p.x = f2bf(av[2 * t].x) | (f2bf(av[2 * t].y) << 16);
      p.y = f2bf(av[2 * t].z) | (f2bf(av[2 * t].w) << 16);
      p.z = f2bf(av[2 * t + 1].x) | (f2bf(av[2 * t + 1].y) << 16);
      p.w = f2bf(av[2 * t + 1].z) | (f2bf(av[2 * t + 1].w) << 16);
      *(uint4*)&Xs[row * 136 + seg * 8] = p;
    }
    unsigned* Tw = (unsigned*)Ts;     // dword view, row stride 68
#pragma unroll
    for (int it = 0; it < 4; ++it) {
      const float* lo = &bv[2 * it].x;
      const float* hi = &bv[2 * it + 1].x;
#pragma unroll
      for (int q = 0; q < 4; ++q) {
        const unsigned val = f2bf(lo[q]) | (f2bf(hi[q]) << 16);
        Tw[(coff + q) * 68 + it * 16 + pr] = val;    // Ts[c][k0..k0+1]
      }
    }

    __syncthreads();

    // ---- MFMA: 8 steps of K=16 ----
#pragma unroll
    for (int s = 0; s < 8; ++s) {
      const bf16x8 af = *(const bf16x8*)&Xs[arow * 136 + s * 16 + half * 8];
      const bf16x8 bf = *(const bf16x8*)&Ts[bcol * 136 + s * 16 + half * 8];
      acc = __builtin_amdgcn_mfma_f32_32x32x16_bf16(af, bf, acc, 0, 0, 0);
    }
    __syncthreads();
  }

  // ---- epilogue: acc -> Cs (stride 68, conflict-free), then prep rows ----
#pragma unroll
  for (int reg = 0; reg < 16; ++reg) {
    const int row = (reg & 3) + 8 * (reg >> 2) + 4 * half;
    Cs[((w & 1) * 32 + row) * 68 + (w >> 1) * 32 + l31] = acc[reg];
  }
  __syncthreads();

#pragma unroll
  for (int pass = 0; pass < 2; ++pass) {
    const int jl = (tid >> 6) + pass * 4;   // local j 0..7
    const int b  = tid & 63;                // local b
    const float4 m0 = *(const float4*)&Cs[b * 68 + jl * 8];
    const float4 m1 = *(const float4*)&Cs[b * 68 + jl * 8 + 4];
    const int j_g = blockIdx.y * 8 + jl;
    const int idx = j_g * NB + b0 + b;
    ((float4*)Mp)[idx * 2]     = m0;
    ((float4*)Mp)[idx * 2 + 1] = m1;
    float s = m0.x * m0.x;
    s = fmaf(m0.y, m0.y, s); s = fmaf(m0.z, m0.z, s); s = fmaf(m0.w, m0.w, s);
    s = fmaf(m1.x, m1.x, s); s = fmaf(m1.y, m1.y, s); s = fmaf(m1.z, m1.z, s);
    s = fmaf(m1.w, m1.w, s);
    na[idx] = s;
    uint4 pk;
    pk.x = f2bf(m0.x) | (f2bf(m0.y) << 16);
    pk.y = f2bf(m0.z) | (f2bf(m0.w) << 16);
    pk.z = f2bf(m1.x) | (f2bf(m1.y) << 16);
    pk.w = f2bf(m1.z) | (f2bf(m1.w) << 16);
    Mb[idx] = pk;
  }
}

// ---------------------------------------------------------------------------
// Kernel 2: pairwise via MFMA + exact per-pair prefilter; corrections go
// straight into out[b][512+j] (out pre-initialized with FEAT_BASE).
// flag iff 0.995*(na+nb) - 2P < 100 (no false negatives; FP rate ~1e-5).
// (byte-identical to the proven 73.7us version)
// ---------------------------------------------------------------------------
__global__ __launch_bounds__(256) void pairwise_kernel(const uint4* __restrict__ Mb,
                                                       const float* __restrict__ na,
                                                       const float* __restrict__ Mp,
                                                       float* __restrict__ out) {
  const int j    = blockIdx.x;
  const int ag   = blockIdx.y;
  const int bh   = blockIdx.z;
  const int tid  = threadIdx.x;
  const int lane = tid & 63;
  const int w    = tid >> 6;
  const int col  = lane & 31;
  const int h    = lane >> 5;
  const int jb   = j * NB;

  __shared__ uint4 Mb_s[513];    // [512] = zeros for K-pad lanes
  __shared__ float nb_s[512];
  __shared__ float na_s[128];

  const int bbeg = bh * 512;
  Mb_s[tid]       = Mb[jb + bbeg + tid];
  Mb_s[tid + 256] = Mb[jb + bbeg + tid + 256];
  nb_s[tid]       = na[jb + bbeg + tid];
  nb_s[tid + 256] = na[jb + bbeg + tid + 256];
  if (tid == 0) Mb_s[512] = uint4{0u, 0u, 0u, 0u};

  const int a0 = ag * 128 + w * 32;
  if (lane < 32) na_s[w * 32 + lane] = na[jb + a0 + lane];

  uint4 araw = uint4{0u, 0u, 0u, 0u};
  if (lane < 32) araw = Mb[jb + a0 + lane];
  const bf16x8 af = __builtin_bit_cast(bf16x8, araw);

  __syncthreads();

  float c995[16];
#pragma unroll
  for (int reg = 0; reg < 16; ++reg) {
    const int row = (reg & 3) + 8 * (reg >> 2) + 4 * h;
    c995[reg] = 0.995f * na_s[w * 32 + row];
  }

  const floatx16 zero = {};

#pragma unroll 2
  for (int bt = 0; bt < 16; ++bt) {
    const int bidx = bt * 32 + col;
    const uint4 braw = Mb_s[lane < 32 ? bidx : 512];
    const bf16x8 bf = __builtin_bit_cast(bf16x8, braw);
    const floatx16 P = __builtin_amdgcn_mfma_f32_32x32x16_bf16(af, bf, zero, 0, 0, 0);
    const float nb_l = nb_s[bidx];
    const float rhs = 100.0f - 0.995f * nb_l;

    float t = fmaf(-2.0f, P[0], c995[0]);
#pragma unroll
    for (int reg = 1; reg < 16; ++reg)
      t = fminf(t, fmaf(-2.0f, P[reg], c995[reg]));

    if (__any(t < rhs)) {   // rare: ~diagonal tiles only
#pragma unroll
      for (int reg = 0; reg < 16; ++reg) {
        if (fmaf(-2.0f, P[reg], c995[reg]) < rhs) {
          const int row = (reg & 3) + 8 * (reg >> 2) + 4 * h;
          const int a = a0 + row;
          const int b = bbeg + bt * 32 + col;
          float corr;
          if (a == b) {
            corr = 1.0f - EXPN10;
          } else {
            const float4 av0 = ((const float4*)Mp)[(jb + a) * 2];
            const float4 av1 = ((const float4*)Mp)[(jb + a) * 2 + 1];
            const float4 bv0 = ((const float4*)Mp)[(jb + b) * 2];
            const float4 bv1 = ((const float4*)Mp)[(jb + b) * 2 + 1];
            float d = av0.x - bv0.x; float sq = d * d;
            d = av0.y - bv0.y; sq = fmaf(d, d, sq);
            d = av0.z - bv0.z; sq = fmaf(d, d, sq);
            d = av0.w - bv0.w; sq = fmaf(d, d, sq);
            d = av1.x - bv1.x; sq = fmaf(d, d, sq);
            d = av1.y - bv1.y; sq = fmaf(d, d, sq);
            d = av1.z - bv1.z; sq = fmaf(d, d, sq);
            d = av1.w - bv1.w; sq = fmaf(d, d, sq);
            const float nrm = sqrtf(sq);
            corr = (nrm < 10.0f) ? (__expf(-nrm) - EXPN10) : 0.0f;
          }
          if (corr != 0.0f) atomicAdd(&out[a * OUTC + NIN + j], corr);
        }
      }
    }
  }
}

// ---------------------------------------------------------------------------
extern "C" void kernel_launch(void* const* d_in, const int* in_sizes, int n_in,
                              void* d_out, int out_size, void* d_ws, size_t ws_size,
                              hipStream_t stream) {
  const float* x = (const float*)d_in[0];
  const float* T = (const float*)d_in[1];
  float* out = (float*)d_out;

  // workspace layout (3.25 MB)
  float* Mp  = (float*)d_ws;                         // [64][1024][8] fp32   2 MB
  float* na  = Mp + (size_t)NJ * NB * NK;            // [64][1024]         256 KB
  uint4* Mb  = (uint4*)(na + (size_t)NJ * NB);       // [64][1024] bf16x8    1 MB

  gemm_fused<<<dim3(16, 8), 256, 0, stream>>>(x, T, Mp, Mb, na, out);
  pairwise_kernel<<<dim3(NJ, 8, 2), 256, 0, stream>>>(Mb, na, Mp, out);
}

// Round 5
// 74.250 us; speedup vs baseline: 2.7721x; 1.0059x over previous
//
#include <hip/hip_runtime.h>

// Problem constants
constexpr int NB  = 1024;
constexpr int NIN = 512;
constexpr int NJ  = 64;
constexpr int NK  = 8;
constexpr int NC  = NJ * NK;          // 512
constexpr int OUTC = NIN + NJ;        // 576
constexpr float EXPN10 = 4.5399929762484854e-05f;
constexpr float FEAT_BASE = 1024.0f * EXPN10;

typedef __bf16 bf16x8 __attribute__((ext_vector_type(8)));
typedef float floatx16 __attribute__((ext_vector_type(16)));

__device__ __forceinline__ unsigned f2bf(float f) {  // RNE fp32->bf16
  unsigned u = __float_as_uint(f);
  u += 0x7FFFu + ((u >> 16) & 1u);
  return u >> 16;
}

// ---------------------------------------------------------------------------
// Kernel 1 (gemm_fused): grid 16x8 = 128 blocks, 4 waves, 34816 B LDS.
// R4 lesson: at 128 blocks the occupancy is 1 wave/SIMD — zero TLP — so each
// z-slice's HBM latency (~900cy) was fully exposed (gemm ~16us inferred).
// R5 fix: software-pipeline the z loop (T14): issue z+1's 16 dwordx4 into a
// SECOND named register buffer before consuming z's buffer; the loads ride
// out under pack+barrier+MFMA+barrier. Two named buffers, fully unrolled —
// no runtime-indexed arrays (rule #20). z0's latency hides under out-init.
// ---------------------------------------------------------------------------
__global__ __launch_bounds__(256) void gemm_fused(const float* __restrict__ x,
                                                  const float* __restrict__ T,
                                                  float* __restrict__ Mp,
                                                  uint4* __restrict__ Mb,
                                                  float* __restrict__ na,
                                                  float* __restrict__ out) {
  __shared__ __align__(16) ushort smem_u[2 * 64 * 136];   // 34816 B
  ushort* Xs = smem_u;              // [64][136] bf16 : A tile (b rows, 128 k)
  ushort* Ts = smem_u + 64 * 136;   // [64][136] bf16 : B tile (c rows, 128 k)
  float*  Cs = (float*)smem_u;      // [64][68] fp32 epilogue tile (overlay)

  const int tid = threadIdx.x;
  const int b0 = blockIdx.x * 64;
  const int c0 = blockIdx.y * 64;

  const int lane = tid & 63;
  const int w    = tid >> 6;
  const int l31  = lane & 31;
  const int half = lane >> 5;
  const int arow = (w & 1) * 32 + l31;
  const int bcol = (w >> 1) * 32 + l31;

  // A-staging thread mapping
  const int xrow = tid >> 4;        // 0..15 -> row = u>>4 handled per t below
  const int xseg = tid & 15;
  // B-transpose thread mapping (fixed across z)
  const int pr   = tid >> 4;        // 0..15 : k-pair index within 32-row group
  const int coff = (tid & 15) * 4;  // 0..60 : c-quad offset
  (void)xrow; (void)xseg;

  float4 avA[8], bvA[8], avB[8], bvB[8];

  auto load_slice = [&](int z, float4 (&av)[8], float4 (&bv)[8]) {
#pragma unroll
    for (int t = 0; t < 4; ++t) {
      const int u = t * 256 + tid;
      const int row = u >> 4, seg = u & 15;
      const size_t base = (size_t)(b0 + row) * NIN + z * 128 + seg * 8;
      av[2 * t]     = *(const float4*)&x[base];
      av[2 * t + 1] = *(const float4*)&x[base + 4];
    }
#pragma unroll
    for (int it = 0; it < 4; ++it) {
      const int k0 = it * 32 + pr * 2;               // local k (even), 0..126
      const size_t base = (size_t)(z * 128 + k0) * NC + c0 + coff;
      bv[2 * it]     = *(const float4*)&T[base];      // row k0
      bv[2 * it + 1] = *(const float4*)&T[base + NC]; // row k0+1
    }
  };

  auto stage_slice = [&](const float4 (&av)[8], const float4 (&bv)[8]) {
#pragma unroll
    for (int t = 0; t < 4; ++t) {
      const int u = t * 256 + tid;
      const int row = u >> 4, seg = u & 15;
      uint4 p;
      p.x = f2bf(av[2 * t].x) | (f2bf(av[2 * t].y) << 16);
      p.y = f2bf(av[2 * t].z) | (f2bf(av[2 * t].w) << 16);
      p.z = f2bf(av[2 * t + 1].x) | (f2bf(av[2 * t + 1].y) << 16);
      p.w = f2bf(av[2 * t + 1].z) | (f2bf(av[2 * t + 1].w) << 16);
      *(uint4*)&Xs[row * 136 + seg * 8] = p;
    }
    unsigned* Tw = (unsigned*)Ts;     // dword view, row stride 68
#pragma unroll
    for (int it = 0; it < 4; ++it) {
      const float* lo = &bv[2 * it].x;
      const float* hi = &bv[2 * it + 1].x;
#pragma unroll
      for (int q = 0; q < 4; ++q) {
        const unsigned val = f2bf(lo[q]) | (f2bf(hi[q]) << 16);
        Tw[(coff + q) * 68 + it * 16 + pr] = val;    // Ts[c][k0..k0+1]
      }
    }
  };

  floatx16 acc = {};
  auto mfma_tile = [&]() {
#pragma unroll
    for (int s = 0; s < 8; ++s) {
      const bf16x8 af = *(const bf16x8*)&Xs[arow * 136 + s * 16 + half * 8];
      const bf16x8 bf = *(const bf16x8*)&Ts[bcol * 136 + s * 16 + half * 8];
      acc = __builtin_amdgcn_mfma_f32_32x32x16_bf16(af, bf, acc, 0, 0, 0);
    }
  };

  // ---- prologue: issue z0 loads first, then out-init covers their latency
  load_slice(0, avA, bvA);

  const int bidf = blockIdx.y * 16 + blockIdx.x;   // 0..127
#pragma unroll
  for (int it = 0; it < 5; ++it) {
    const int li = it * 256 + tid;
    if (li < 1152) {                                 // 147456/128 float4 per block
      const int gi = bidf * 1152 + li;
      const int b = gi / (OUTC / 4);                 // /144 -> magic mul
      const int r = gi - b * (OUTC / 4);
      float4 v;
      if (r < NIN / 4) v = ((const float4*)x)[b * (NIN / 4) + r];
      else v = float4{FEAT_BASE, FEAT_BASE, FEAT_BASE, FEAT_BASE};
      ((float4*)out)[gi] = v;
    }
  }

  // ---- pipelined z loop (fully unrolled, two named buffers) ----
  // z0
  load_slice(1, avB, bvB);          // prefetch z1 (issued before z0 consume)
  stage_slice(avA, bvA);
  __syncthreads();
  mfma_tile();
  __syncthreads();
  // z1
  load_slice(2, avA, bvA);          // prefetch z2
  stage_slice(avB, bvB);
  __syncthreads();
  mfma_tile();
  __syncthreads();
  // z2
  load_slice(3, avB, bvB);          // prefetch z3
  stage_slice(avA, bvA);
  __syncthreads();
  mfma_tile();
  __syncthreads();
  // z3
  stage_slice(avB, bvB);
  __syncthreads();
  mfma_tile();
  __syncthreads();                  // protect LDS before Cs overlay

  // ---- epilogue: acc -> Cs (stride 68, conflict-free), then prep rows ----
#pragma unroll
  for (int reg = 0; reg < 16; ++reg) {
    const int row = (reg & 3) + 8 * (reg >> 2) + 4 * half;
    Cs[((w & 1) * 32 + row) * 68 + (w >> 1) * 32 + l31] = acc[reg];
  }
  __syncthreads();

#pragma unroll
  for (int pass = 0; pass < 2; ++pass) {
    const int jl = (tid >> 6) + pass * 4;   // local j 0..7
    const int b  = tid & 63;                // local b
    const float4 m0 = *(const float4*)&Cs[b * 68 + jl * 8];
    const float4 m1 = *(const float4*)&Cs[b * 68 + jl * 8 + 4];
    const int j_g = blockIdx.y * 8 + jl;
    const int idx = j_g * NB + b0 + b;
    ((float4*)Mp)[idx * 2]     = m0;
    ((float4*)Mp)[idx * 2 + 1] = m1;
    float s = m0.x * m0.x;
    s = fmaf(m0.y, m0.y, s); s = fmaf(m0.z, m0.z, s); s = fmaf(m0.w, m0.w, s);
    s = fmaf(m1.x, m1.x, s); s = fmaf(m1.y, m1.y, s); s = fmaf(m1.z, m1.z, s);
    s = fmaf(m1.w, m1.w, s);
    na[idx] = s;
    uint4 pk;
    pk.x = f2bf(m0.x) | (f2bf(m0.y) << 16);
    pk.y = f2bf(m0.z) | (f2bf(m0.w) << 16);
    pk.z = f2bf(m1.x) | (f2bf(m1.y) << 16);
    pk.w = f2bf(m1.z) | (f2bf(m1.w) << 16);
    Mb[idx] = pk;
  }
}

// ---------------------------------------------------------------------------
// Kernel 2: pairwise via MFMA + exact per-pair prefilter; corrections go
// straight into out[b][512+j] (out pre-initialized with FEAT_BASE).
// flag iff 0.995*(na+nb) - 2P < 100 (no false negatives; FP rate ~1e-5).
// (byte-identical to the proven 73.7us version)
// ---------------------------------------------------------------------------
__global__ __launch_bounds__(256) void pairwise_kernel(const uint4* __restrict__ Mb,
                                                       const float* __restrict__ na,
                                                       const float* __restrict__ Mp,
                                                       float* __restrict__ out) {
  const int j    = blockIdx.x;
  const int ag   = blockIdx.y;
  const int bh   = blockIdx.z;
  const int tid  = threadIdx.x;
  const int lane = tid & 63;
  const int w    = tid >> 6;
  const int col  = lane & 31;
  const int h    = lane >> 5;
  const int jb   = j * NB;

  __shared__ uint4 Mb_s[513];    // [512] = zeros for K-pad lanes
  __shared__ float nb_s[512];
  __shared__ float na_s[128];

  const int bbeg = bh * 512;
  Mb_s[tid]       = Mb[jb + bbeg + tid];
  Mb_s[tid + 256] = Mb[jb + bbeg + tid + 256];
  nb_s[tid]       = na[jb + bbeg + tid];
  nb_s[tid + 256] = na[jb + bbeg + tid + 256];
  if (tid == 0) Mb_s[512] = uint4{0u, 0u, 0u, 0u};

  const int a0 = ag * 128 + w * 32;
  if (lane < 32) na_s[w * 32 + lane] = na[jb + a0 + lane];

  uint4 araw = uint4{0u, 0u, 0u, 0u};
  if (lane < 32) araw = Mb[jb + a0 + lane];
  const bf16x8 af = __builtin_bit_cast(bf16x8, araw);

  __syncthreads();

  float c995[16];
#pragma unroll
  for (int reg = 0; reg < 16; ++reg) {
    const int row = (reg & 3) + 8 * (reg >> 2) + 4 * h;
    c995[reg] = 0.995f * na_s[w * 32 + row];
  }

  const floatx16 zero = {};

#pragma unroll 2
  for (int bt = 0; bt < 16; ++bt) {
    const int bidx = bt * 32 + col;
    const uint4 braw = Mb_s[lane < 32 ? bidx : 512];
    const bf16x8 bf = __builtin_bit_cast(bf16x8, braw);
    const floatx16 P = __builtin_amdgcn_mfma_f32_32x32x16_bf16(af, bf, zero, 0, 0, 0);
    const float nb_l = nb_s[bidx];
    const float rhs = 100.0f - 0.995f * nb_l;

    float t = fmaf(-2.0f, P[0], c995[0]);
#pragma unroll
    for (int reg = 1; reg < 16; ++reg)
      t = fminf(t, fmaf(-2.0f, P[reg], c995[reg]));

    if (__any(t < rhs)) {   // rare: ~diagonal tiles only
#pragma unroll
      for (int reg = 0; reg < 16; ++reg) {
        if (fmaf(-2.0f, P[reg], c995[reg]) < rhs) {
          const int row = (reg & 3) + 8 * (reg >> 2) + 4 * h;
          const int a = a0 + row;
          const int b = bbeg + bt * 32 + col;
          float corr;
          if (a == b) {
            corr = 1.0f - EXPN10;
          } else {
            const float4 av0 = ((const float4*)Mp)[(jb + a) * 2];
            const float4 av1 = ((const float4*)Mp)[(jb + a) * 2 + 1];
            const float4 bv0 = ((const float4*)Mp)[(jb + b) * 2];
            const float4 bv1 = ((const float4*)Mp)[(jb + b) * 2 + 1];
            float d = av0.x - bv0.x; float sq = d * d;
            d = av0.y - bv0.y; sq = fmaf(d, d, sq);
            d = av0.z - bv0.z; sq = fmaf(d, d, sq);
            d = av0.w - bv0.w; sq = fmaf(d, d, sq);
            d = av1.x - bv1.x; sq = fmaf(d, d, sq);
            d = av1.y - bv1.y; sq = fmaf(d, d, sq);
            d = av1.z - bv1.z; sq = fmaf(d, d, sq);
            d = av1.w - bv1.w; sq = fmaf(d, d, sq);
            const float nrm = sqrtf(sq);
            corr = (nrm < 10.0f) ? (__expf(-nrm) - EXPN10) : 0.0f;
          }
          if (corr != 0.0f) atomicAdd(&out[a * OUTC + NIN + j], corr);
        }
      }
    }
  }
}

// ---------------------------------------------------------------------------
extern "C" void kernel_launch(void* const* d_in, const int* in_sizes, int n_in,
                              void* d_out, int out_size, void* d_ws, size_t ws_size,
                              hipStream_t stream) {
  const float* x = (const float*)d_in[0];
  const float* T = (const float*)d_in[1];
  float* out = (float*)d_out;

  // workspace layout (3.25 MB)
  float* Mp  = (float*)d_ws;                         // [64][1024][8] fp32   2 MB
  float* na  = Mp + (size_t)NJ * NB * NK;            // [64][1024]         256 KB
  uint4* Mb  = (uint4*)(na + (size_t)NJ * NB);       // [64][1024] bf16x8    1 MB

  gemm_fused<<<dim3(16, 8), 256, 0, stream>>>(x, T, Mp, Mb, na, out);
  pairwise_kernel<<<dim3(NJ, 8, 2), 256, 0, stream>>>(Mb, na, Mp, out);
}